// Round 1
// baseline (604.743 us; speedup 1.0000x reference)
//
#include <hip/hip_runtime.h>
#include <hip/hip_bf16.h>
#include <math.h>

// GPT decoder layer, MI355X/gfx950. bf16 MFMA GEMMs + fused flash attention.
// B=4 S=2048 D=1024 H=16 DH=64 F=4096.  Workspace layout (bytes):
//   [0,6M)      WqkvT  bf16 [3072][1024]   (pre-transposed, k-contiguous)
//   [6M,8M)     WoT    bf16 [1024][1024]
//   [8M,16M)    W1T    bf16 [4096][1024]
//   [16M,24M)   W2T    bf16 [1024][4096]
//   [24M,40M)   hbuf   bf16 [8192][1024]   (h -> attn_out -> h2, reused)
//   [40M,104M)  big    bf16                (QKV [8192][3072], later ff1 [8192][4096])

#define Bz 4
#define Sz 2048
#define Dz 1024
#define Hz 16
#define DHz 64
#define Fz 4096
#define Mz 8192

typedef float f32x4 __attribute__((ext_vector_type(4)));
typedef __bf16 bf16x8 __attribute__((ext_vector_type(8)));
typedef short s16x4 __attribute__((ext_vector_type(4)));
typedef short s16x8 __attribute__((ext_vector_type(8)));

#define GLOAD_LDS16(g, l)                                                                   \
  __builtin_amdgcn_global_load_lds((const __attribute__((address_space(1))) unsigned int*)(g), \
                                   (__attribute__((address_space(3))) unsigned int*)(l), 16, 0, 0)

static __device__ __forceinline__ unsigned short f2bu(float f) {
  unsigned int u = __float_as_uint(f);
  u += 0x7fffu + ((u >> 16) & 1u);   // RNE to bf16
  return (unsigned short)(u >> 16);
}

static __device__ __forceinline__ f32x4 mfma32(bf16x8 a, bf16x8 b, f32x4 c) {
  return __builtin_amdgcn_mfma_f32_16x16x32_bf16(a, b, c, 0, 0, 0);
}
static __device__ __forceinline__ f32x4 mfma16(s16x4 a, s16x4 b, f32x4 c) {
#if __has_builtin(__builtin_amdgcn_mfma_f32_16x16x16bf16_1k)
  return __builtin_amdgcn_mfma_f32_16x16x16bf16_1k(a, b, c, 0, 0, 0);
#else
  asm("v_mfma_f32_16x16x16_bf16 %0, %1, %2, %0" : "+v"(c) : "v"(a), "v"(b));
  return c;
#endif
}

// ---------------- weight packing ----------------

__global__ __launch_bounds__(256) void pack_qkv(
    const float* __restrict__ wq, const float* __restrict__ wk, const float* __restrict__ wv,
    unsigned short* __restrict__ outW)  // [3072][1024], row n = proj*1024 + h*64 + e, col = d
{
  int idx = blockIdx.x * 256 + threadIdx.x;
  int n = idx >> 10, d = idx & 1023;
  int proj = n >> 10, nn = n & 1023;
  int hh = nn >> 6, e = nn & 63;
  const float* w = proj == 0 ? wq : (proj == 1 ? wk : wv);
  outW[idx] = f2bu(w[((size_t)hh * Dz + d) * DHz + e]);
}

__global__ __launch_bounds__(256) void transpose_f32_to_bf16(
    const float* __restrict__ in, unsigned short* __restrict__ out, int R, int C)
{ // in [R][C] fp32 -> out [C][R] bf16
  __shared__ float tile[32][33];
  int c0 = blockIdx.x * 32, r0 = blockIdx.y * 32;
  int x = threadIdx.x, y = threadIdx.y;
#pragma unroll
  for (int i = 0; i < 32; i += 8)
    tile[y + i][x] = in[(size_t)(r0 + y + i) * C + c0 + x];
  __syncthreads();
#pragma unroll
  for (int i = 0; i < 32; i += 8)
    out[(size_t)(c0 + y + i) * R + r0 + x] = f2bu(tile[x][y + i]);
}

// ---------------- layernorm ----------------

__global__ __launch_bounds__(256) void ln_kernel(
    const float* __restrict__ x, const float* __restrict__ gamma, const float* __restrict__ beta,
    unsigned short* __restrict__ outH)
{
  const int row = blockIdx.x;
  const int tid = threadIdx.x;
  const float4 v = ((const float4*)(x + (size_t)row * Dz))[tid];
  float s = v.x + v.y + v.z + v.w;
  float s2 = v.x * v.x + v.y * v.y + v.z * v.z + v.w * v.w;
#pragma unroll
  for (int o = 32; o > 0; o >>= 1) {
    s += __shfl_xor(s, o);
    s2 += __shfl_xor(s2, o);
  }
  __shared__ float ss[4], ss2[4];
  if ((tid & 63) == 0) { ss[tid >> 6] = s; ss2[tid >> 6] = s2; }
  __syncthreads();
  s = ss[0] + ss[1] + ss[2] + ss[3];
  s2 = ss2[0] + ss2[1] + ss2[2] + ss2[3];
  const float mean = s * (1.0f / Dz);
  const float rstd = rsqrtf(s2 * (1.0f / Dz) - mean * mean + 1e-5f);
  const float4 g4 = ((const float4*)gamma)[tid];
  const float4 b4 = ((const float4*)beta)[tid];
  ushort4 o;
  o.x = f2bu((v.x - mean) * rstd * g4.x + b4.x);
  o.y = f2bu((v.y - mean) * rstd * g4.y + b4.y);
  o.z = f2bu((v.z - mean) * rstd * g4.z + b4.z);
  o.w = f2bu((v.w - mean) * rstd * g4.w + b4.w);
  ((ushort4*)(outH + (size_t)row * Dz))[tid] = o;
}

// ---------------- GEMM: C[M,N] = A[M,K](bf16) @ BT[N,K]^T(bf16), m97-style ----------------

enum { EPI_BF16 = 0, EPI_GELU_BF16 = 1, EPI_RES_F32 = 2, EPI_BIAS_RES_F32 = 3 };

template <int EPI>
__global__ __launch_bounds__(256) void gemm_kernel(
    const unsigned short* __restrict__ A,   // [M,K] bf16
    const unsigned short* __restrict__ BT,  // [N,K] bf16
    int M, int N, int K,
    const float* bias, const float* resid,  // resid/outf may alias: no __restrict__
    unsigned short* outb, float* outf)
{
  __shared__ unsigned short As[128 * 32];  // [row][32k], 16B chunk c XOR-swizzled by row&3
  __shared__ unsigned short Bs[128 * 32];
  const int tid = threadIdx.x;
  const int lane = tid & 63;
  const int m0 = blockIdx.y * 128;
  const int n0 = blockIdx.x * 128;
  const int wm = ((tid >> 7) & 1) * 64;
  const int wn = ((tid >> 6) & 1) * 64;
  const int rsel = lane & 15;
  const int kgrp = lane >> 4;

  f32x4 acc[4][4] = {};

  const int kTiles = K >> 5;
  for (int kt = 0; kt < kTiles; ++kt) {
    if (kt) __syncthreads();
    const int kOff = kt * 32;
#pragma unroll
    for (int r = 0; r < 2; ++r) {
      int c = r * 256 + tid;           // 512 chunks of 16B per tile
      int row = c >> 2;
      int kcs = (c & 3) ^ (row & 3);   // pre-swizzled global source, linear LDS dest
      GLOAD_LDS16(A + (size_t)(m0 + row) * K + kOff + kcs * 8, &As[c * 8]);
      GLOAD_LDS16(BT + (size_t)(n0 + row) * K + kOff + kcs * 8, &Bs[c * 8]);
    }
    __syncthreads();
    bf16x8 af[4], bfr[4];
#pragma unroll
    for (int mf = 0; mf < 4; ++mf) {
      int row = wm + mf * 16 + rsel;
      af[mf] = *(const bf16x8*)&As[row * 32 + ((kgrp ^ (row & 3)) * 8)];
    }
#pragma unroll
    for (int nf = 0; nf < 4; ++nf) {
      int row = wn + nf * 16 + rsel;
      bfr[nf] = *(const bf16x8*)&Bs[row * 32 + ((kgrp ^ (row & 3)) * 8)];
    }
#pragma unroll
    for (int mf = 0; mf < 4; ++mf)
#pragma unroll
      for (int nf = 0; nf < 4; ++nf)
        acc[mf][nf] = mfma32(af[mf], bfr[nf], acc[mf][nf]);
  }

#pragma unroll
  for (int mf = 0; mf < 4; ++mf) {
#pragma unroll
    for (int nf = 0; nf < 4; ++nf) {
      const int n = n0 + wn + nf * 16 + rsel;
#pragma unroll
      for (int j = 0; j < 4; ++j) {
        const int m = m0 + wm + mf * 16 + kgrp * 4 + j;
        const size_t idx = (size_t)m * N + n;
        float v = acc[mf][nf][j];
        if constexpr (EPI == EPI_BF16) {
          outb[idx] = f2bu(v);
        } else if constexpr (EPI == EPI_GELU_BF16) {
          v += bias[n];
          v = 0.5f * v * (1.0f + erff(v * 0.70710678118654752f));
          outb[idx] = f2bu(v);
        } else if constexpr (EPI == EPI_RES_F32) {
          outf[idx] = v + resid[idx];
        } else {
          outf[idx] = v + bias[n] + resid[idx];
        }
      }
    }
  }
}

// ---------------- fused causal flash attention ----------------
// block = (q-tile of 64) x (head) x (batch); 4 waves, wave w owns q rows w*16..+16.
// S^T = K_tile @ Q^T via mfma 16x16x32 (C: col=q=lane&15, row=key=(lane>>4)*4+reg)
// -> P^T already in the B-frag layout of mfma 16x16x16 for O^T = V^T @ P^T. Zero shuffles.

__global__ __launch_bounds__(256) void attn_kernel(
    const unsigned short* __restrict__ QKV,  // [Mz][3072] bf16 (q|k|v, feature h*64+e)
    unsigned short* __restrict__ outA)       // [Mz][Dz]  bf16
{
  __shared__ unsigned short Kt[64 * 64];  // [key][d], 16B d-chunk XOR-swizzled by key&7
  __shared__ unsigned short Vt[64 * 64];  // [d][key], 8B key-chunk XOR-swizzled by d&15
  const int qt = blockIdx.x;
  const int hh = blockIdx.y;
  const int bb = blockIdx.z;
  const int tid = threadIdx.x;
  const int lane = tid & 63;
  const int w = tid >> 6;
  const int rsel = lane & 15;
  const int kgrp = lane >> 4;
  const int qb = qt * 64;
  const int qg = qb + w * 16 + rsel;
  const size_t rowQ = (size_t)(bb * Sz + qg) * 3072 + hh * 64;

  const bf16x8 qf0 = *(const bf16x8*)&QKV[rowQ + kgrp * 8];        // B-frag: col=q, k=d 0..31
  const bf16x8 qf1 = *(const bf16x8*)&QKV[rowQ + 32 + kgrp * 8];   // d 32..63

  f32x4 accO[4] = {};  // O^T: row=d=(df*16 + kgrp*4 + j), col=q=rsel
  float mrun = -INFINITY, lrun = 0.0f;

  for (int kt = 0; kt <= qt; ++kt) {
    const int kb = kt * 64;
    if (kt) __syncthreads();  // prev tile's LDS reads done before overwrite
    // stage K (global_load_lds, source pre-swizzled)
#pragma unroll
    for (int r = 0; r < 2; ++r) {
      int c = r * 256 + tid;
      int key = c >> 3;
      int dcs = (c & 7) ^ (key & 7);
      GLOAD_LDS16(QKV + (size_t)(bb * Sz + kb + key) * 3072 + 1024 + hh * 64 + dcs * 8,
                  &Kt[c * 8]);
    }
    // stage V transposed (reg->LDS scalar scatter, swizzled)
#pragma unroll
    for (int r = 0; r < 2; ++r) {
      int c = r * 256 + tid;
      int key = c >> 3;
      int dc = c & 7;
      s16x8 vv = *(const s16x8*)&QKV[(size_t)(bb * Sz + kb + key) * 3072 + 2048 + hh * 64 + dc * 8];
#pragma unroll
      for (int j = 0; j < 8; ++j) {
        int d = dc * 8 + j;
        Vt[d * 64 + (((key >> 2) ^ (d & 15)) * 4) + (key & 3)] = (unsigned short)vv[j];
      }
    }
    __syncthreads();

    // S^T = K @ Q^T
    f32x4 sc[4];
#pragma unroll
    for (int kf = 0; kf < 4; ++kf) {
      int key = kf * 16 + rsel;
      bf16x8 k0 = *(const bf16x8*)&Kt[key * 64 + ((kgrp ^ (key & 7)) * 8)];
      bf16x8 k1 = *(const bf16x8*)&Kt[key * 64 + (((4 + kgrp) ^ (key & 7)) * 8)];
      f32x4 s = {};
      s = mfma32(k0, qf0, s);
      s = mfma32(k1, qf1, s);
      sc[kf] = s;
    }

    // online softmax (q is lane-local: col=rsel)
    float p[4][4];
    float tmax = -INFINITY;
    const bool edge = (kt == qt);
#pragma unroll
    for (int kf = 0; kf < 4; ++kf)
#pragma unroll
      for (int j = 0; j < 4; ++j) {
        float v = sc[kf][j] * 0.125f;  // mask-then-scale == scale-then-mask (-inf)
        if (edge) {
          int keyg = kb + kf * 16 + kgrp * 4 + j;
          if (keyg > qg) v = -INFINITY;
        }
        p[kf][j] = v;
        tmax = fmaxf(tmax, v);
      }
    tmax = fmaxf(tmax, __shfl_xor(tmax, 16));
    tmax = fmaxf(tmax, __shfl_xor(tmax, 32));
    const float mnew = fmaxf(mrun, tmax);
    const float corr = expf(mrun - mnew);
    float psum = 0.0f;
#pragma unroll
    for (int kf = 0; kf < 4; ++kf)
#pragma unroll
      for (int j = 0; j < 4; ++j) {
        float e = expf(p[kf][j] - mnew);
        p[kf][j] = e;
        psum += e;
      }
    psum += __shfl_xor(psum, 16);
    psum += __shfl_xor(psum, 32);
    lrun = lrun * corr + psum;
    mrun = mnew;
#pragma unroll
    for (int df = 0; df < 4; ++df) accO[df] *= corr;

    // P^T -> bf16 B-frags (reg j == key (kgrp*4+j): exact 16x16x16 B layout)
    s16x4 pb[4];
#pragma unroll
    for (int kf = 0; kf < 4; ++kf) {
      s16x4 t;
#pragma unroll
      for (int j = 0; j < 4; ++j) t[j] = (short)f2bu(p[kf][j]);
      pb[kf] = t;
    }

    // O^T += V^T @ P^T
#pragma unroll
    for (int df = 0; df < 4; ++df) {
      int d = df * 16 + rsel;
#pragma unroll
      for (int kf = 0; kf < 4; ++kf) {
        int kc = kf * 4 + kgrp;
        s16x4 vf = *(const s16x4*)&Vt[d * 64 + ((kc ^ (d & 15)) * 4)];
        accO[df] = mfma16(vf, pb[kf], accO[df]);
      }
    }
  }

  const float rl = 1.0f / lrun;
  const size_t orow = (size_t)(bb * Sz + qg) * Dz + hh * 64;
#pragma unroll
  for (int df = 0; df < 4; ++df) {
    s16x4 o;
#pragma unroll
    for (int j = 0; j < 4; ++j) o[j] = (short)f2bu(accO[df][j] * rl);
    *(s16x4*)&outA[orow + df * 16 + kgrp * 4] = o;
  }
}

// ---------------- launch ----------------

extern "C" void kernel_launch(void* const* d_in, const int* in_sizes, int n_in,
                              void* d_out, int out_size, void* d_ws, size_t ws_size,
                              hipStream_t stream) {
  const float* x   = (const float*)d_in[0];
  // d_in[1] = mask (causal, known) — unused
  const float* wq  = (const float*)d_in[2];
  const float* wk  = (const float*)d_in[3];
  const float* wv  = (const float*)d_in[4];
  const float* wo  = (const float*)d_in[5];
  const float* w1  = (const float*)d_in[6];
  const float* b1  = (const float*)d_in[7];
  const float* w2  = (const float*)d_in[8];
  const float* b2  = (const float*)d_in[9];
  const float* g1  = (const float*)d_in[10];
  const float* be1 = (const float*)d_in[11];
  const float* g2  = (const float*)d_in[12];
  const float* be2 = (const float*)d_in[13];
  float* out = (float*)d_out;

  char* ws = (char*)d_ws;
  unsigned short* WqkvT = (unsigned short*)(ws);
  unsigned short* WoT   = (unsigned short*)(ws + 6291456);
  unsigned short* W1T   = (unsigned short*)(ws + 8388608);
  unsigned short* W2T   = (unsigned short*)(ws + 16777216);
  unsigned short* hbuf  = (unsigned short*)(ws + 25165824);
  unsigned short* big   = (unsigned short*)(ws + 41943040);  // QKV, later ff1

  dim3 tb(32, 8);
  pack_qkv<<<12288, 256, 0, stream>>>(wq, wk, wv, WqkvT);
  transpose_f32_to_bf16<<<dim3(32, 32), tb, 0, stream>>>(wo, WoT, 1024, 1024);
  transpose_f32_to_bf16<<<dim3(128, 32), tb, 0, stream>>>(w1, W1T, 1024, 4096);
  transpose_f32_to_bf16<<<dim3(32, 128), tb, 0, stream>>>(w2, W2T, 4096, 1024);

  ln_kernel<<<Mz, 256, 0, stream>>>(x, g1, be1, hbuf);
  gemm_kernel<EPI_BF16><<<dim3(24, 64), 256, 0, stream>>>(
      hbuf, WqkvT, Mz, 3072, 1024, nullptr, nullptr, big, nullptr);
  attn_kernel<<<dim3(32, 16, 4), 256, 0, stream>>>(big, hbuf);
  gemm_kernel<EPI_RES_F32><<<dim3(8, 64), 256, 0, stream>>>(
      hbuf, WoT, Mz, 1024, 1024, nullptr, x, nullptr, out);
  ln_kernel<<<Mz, 256, 0, stream>>>(out, g2, be2, hbuf);
  gemm_kernel<EPI_GELU_BF16><<<dim3(32, 64), 256, 0, stream>>>(
      hbuf, W1T, Mz, Fz, 1024, b1, nullptr, big, nullptr);
  gemm_kernel<EPI_BIAS_RES_F32><<<dim3(8, 64), 256, 0, stream>>>(
      big, W2T, Mz, 1024, Fz, b2, out, nullptr, out);
}

// Round 2
// 512.658 us; speedup vs baseline: 1.1796x; 1.1796x over previous
//
#include <hip/hip_runtime.h>
#include <hip/hip_bf16.h>
#include <math.h>

// GPT decoder layer, MI355X/gfx950. bf16 MFMA GEMMs + fused flash attention.
// B=4 S=2048 D=1024 H=16 DH=64 F=4096.  Workspace layout (bytes):
//   [0,6M)      WqkvT  bf16 [3072][1024]   (pre-transposed, k-contiguous)
//   [6M,8M)     WoT    bf16 [1024][1024]
//   [8M,16M)    W1T    bf16 [4096][1024]
//   [16M,24M)   W2T    bf16 [1024][4096]
//   [24M,40M)   hbuf   bf16 [8192][1024]   (h -> attn_out -> h2, reused)
//   [40M,104M)  big    bf16                (QKV [8192][3072], later ff1 [8192][4096])

#define Bz 4
#define Sz 2048
#define Dz 1024
#define Hz 16
#define DHz 64
#define Fz 4096
#define Mz 8192

typedef float f32x4 __attribute__((ext_vector_type(4)));
typedef __bf16 bf16x8 __attribute__((ext_vector_type(8)));
typedef short s16x4 __attribute__((ext_vector_type(4)));

#define GLOAD_LDS16(g, l)                                                                   \
  __builtin_amdgcn_global_load_lds((const __attribute__((address_space(1))) unsigned int*)(g), \
                                   (__attribute__((address_space(3))) unsigned int*)(l), 16, 0, 0)

static __device__ __forceinline__ unsigned short f2bu(float f) {
  unsigned int u = __float_as_uint(f);
  u += 0x7fffu + ((u >> 16) & 1u);   // RNE to bf16
  return (unsigned short)(u >> 16);
}

static __device__ __forceinline__ f32x4 mfma32(bf16x8 a, bf16x8 b, f32x4 c) {
  return __builtin_amdgcn_mfma_f32_16x16x32_bf16(a, b, c, 0, 0, 0);
}
static __device__ __forceinline__ f32x4 mfma16(s16x4 a, s16x4 b, f32x4 c) {
#if __has_builtin(__builtin_amdgcn_mfma_f32_16x16x16bf16_1k)
  return __builtin_amdgcn_mfma_f32_16x16x16bf16_1k(a, b, c, 0, 0, 0);
#else
  asm("v_mfma_f32_16x16x16_bf16 %0, %1, %2, %0" : "+v"(c) : "v"(a), "v"(b));
  return c;
#endif
}

// hardware transpose read: lane l elem j <- lds[base + (l&15) + j*16 + (l>>4)*64] (bf16 elems)
template <int OFF>
static __device__ __forceinline__ s16x4 tr16(unsigned addr) {
  s16x4 r;
  asm volatile("ds_read_b64_tr_b16 %0, %1 offset:%2" : "=v"(r) : "v"(addr), "i"(OFF));
  return r;
}

// ---------------- weight packing ----------------

__global__ __launch_bounds__(256) void pack_qkv(
    const float* __restrict__ wq, const float* __restrict__ wk, const float* __restrict__ wv,
    unsigned short* __restrict__ outW)  // [3072][1024], row n = proj*1024 + h*64 + e, col = d
{
  int idx = blockIdx.x * 256 + threadIdx.x;
  int n = idx >> 10, d = idx & 1023;
  int proj = n >> 10, nn = n & 1023;
  int hh = nn >> 6, e = nn & 63;
  const float* w = proj == 0 ? wq : (proj == 1 ? wk : wv);
  outW[idx] = f2bu(w[((size_t)hh * Dz + d) * DHz + e]);
}

__global__ __launch_bounds__(256) void transpose_f32_to_bf16(
    const float* __restrict__ in, unsigned short* __restrict__ out, int R, int C)
{ // in [R][C] fp32 -> out [C][R] bf16
  __shared__ float tile[32][33];
  int c0 = blockIdx.x * 32, r0 = blockIdx.y * 32;
  int x = threadIdx.x, y = threadIdx.y;
#pragma unroll
  for (int i = 0; i < 32; i += 8)
    tile[y + i][x] = in[(size_t)(r0 + y + i) * C + c0 + x];
  __syncthreads();
#pragma unroll
  for (int i = 0; i < 32; i += 8)
    out[(size_t)(c0 + y + i) * R + r0 + x] = f2bu(tile[x][y + i]);
}

// ---------------- layernorm ----------------

__global__ __launch_bounds__(256) void ln_kernel(
    const float* __restrict__ x, const float* __restrict__ gamma, const float* __restrict__ beta,
    unsigned short* __restrict__ outH)
{
  const int row = blockIdx.x;
  const int tid = threadIdx.x;
  const float4 v = ((const float4*)(x + (size_t)row * Dz))[tid];
  float s = v.x + v.y + v.z + v.w;
  float s2 = v.x * v.x + v.y * v.y + v.z * v.z + v.w * v.w;
#pragma unroll
  for (int o = 32; o > 0; o >>= 1) {
    s += __shfl_xor(s, o);
    s2 += __shfl_xor(s2, o);
  }
  __shared__ float ss[4], ss2[4];
  if ((tid & 63) == 0) { ss[tid >> 6] = s; ss2[tid >> 6] = s2; }
  __syncthreads();
  s = ss[0] + ss[1] + ss[2] + ss[3];
  s2 = ss2[0] + ss2[1] + ss2[2] + ss2[3];
  const float mean = s * (1.0f / Dz);
  const float rstd = rsqrtf(s2 * (1.0f / Dz) - mean * mean + 1e-5f);
  const float4 g4 = ((const float4*)gamma)[tid];
  const float4 b4 = ((const float4*)beta)[tid];
  ushort4 o;
  o.x = f2bu((v.x - mean) * rstd * g4.x + b4.x);
  o.y = f2bu((v.y - mean) * rstd * g4.y + b4.y);
  o.z = f2bu((v.z - mean) * rstd * g4.z + b4.z);
  o.w = f2bu((v.w - mean) * rstd * g4.w + b4.w);
  ((ushort4*)(outH + (size_t)row * Dz))[tid] = o;
}

// ---------------- GEMM: C[M,N] = A[M,K](bf16) @ BT[N,K]^T(bf16), m97-style ----------------

enum { EPI_BF16 = 0, EPI_GELU_BF16 = 1, EPI_RES_F32 = 2, EPI_BIAS_RES_F32 = 3 };

template <int EPI>
__global__ __launch_bounds__(256) void gemm_kernel(
    const unsigned short* __restrict__ A,   // [M,K] bf16
    const unsigned short* __restrict__ BT,  // [N,K] bf16
    int M, int N, int K,
    const float* bias, const float* resid,  // resid/outf may alias: no __restrict__
    unsigned short* outb, float* outf)
{
  __shared__ unsigned short As[128 * 32];  // [row][32k], 16B chunk c XOR-swizzled by row&3
  __shared__ unsigned short Bs[128 * 32];
  const int tid = threadIdx.x;
  const int lane = tid & 63;
  const int m0 = blockIdx.y * 128;
  const int n0 = blockIdx.x * 128;
  const int wm = ((tid >> 7) & 1) * 64;
  const int wn = ((tid >> 6) & 1) * 64;
  const int rsel = lane & 15;
  const int kgrp = lane >> 4;

  f32x4 acc[4][4] = {};

  const int kTiles = K >> 5;
  for (int kt = 0; kt < kTiles; ++kt) {
    if (kt) __syncthreads();
    const int kOff = kt * 32;
#pragma unroll
    for (int r = 0; r < 2; ++r) {
      int c = r * 256 + tid;           // 512 chunks of 16B per tile
      int row = c >> 2;
      int kcs = (c & 3) ^ (row & 3);   // pre-swizzled global source, linear LDS dest
      GLOAD_LDS16(A + (size_t)(m0 + row) * K + kOff + kcs * 8, &As[c * 8]);
      GLOAD_LDS16(BT + (size_t)(n0 + row) * K + kOff + kcs * 8, &Bs[c * 8]);
    }
    __syncthreads();
    bf16x8 af[4], bfr[4];
#pragma unroll
    for (int mf = 0; mf < 4; ++mf) {
      int row = wm + mf * 16 + rsel;
      af[mf] = *(const bf16x8*)&As[row * 32 + ((kgrp ^ (row & 3)) * 8)];
    }
#pragma unroll
    for (int nf = 0; nf < 4; ++nf) {
      int row = wn + nf * 16 + rsel;
      bfr[nf] = *(const bf16x8*)&Bs[row * 32 + ((kgrp ^ (row & 3)) * 8)];
    }
#pragma unroll
    for (int mf = 0; mf < 4; ++mf)
#pragma unroll
      for (int nf = 0; nf < 4; ++nf)
        acc[mf][nf] = mfma32(af[mf], bfr[nf], acc[mf][nf]);
  }

#pragma unroll
  for (int mf = 0; mf < 4; ++mf) {
#pragma unroll
    for (int nf = 0; nf < 4; ++nf) {
      const int n = n0 + wn + nf * 16 + rsel;
#pragma unroll
      for (int j = 0; j < 4; ++j) {
        const int m = m0 + wm + mf * 16 + kgrp * 4 + j;
        const size_t idx = (size_t)m * N + n;
        float v = acc[mf][nf][j];
        if constexpr (EPI == EPI_BF16) {
          outb[idx] = f2bu(v);
        } else if constexpr (EPI == EPI_GELU_BF16) {
          v += bias[n];
          v = 0.5f * v * (1.0f + erff(v * 0.70710678118654752f));
          outb[idx] = f2bu(v);
        } else if constexpr (EPI == EPI_RES_F32) {
          outf[idx] = v + resid[idx];
        } else {
          outf[idx] = v + bias[n] + resid[idx];
        }
      }
    }
  }
}

// ---------------- fused causal flash attention ----------------
// Block = pair of q-tiles {pi, 31-pi} x head x batch: every block does exactly 33
// compute-tiles (perfect balance) and the pair SHARES K/V staging. 4 waves, wave w
// owns q rows w*16..+16 of each q-tile.
// S^T = K_tile @ Q^T via mfma 16x16x32 (C: col=q=lane&15, row=key=(lane>>4)*4+reg)
// -> P^T already in the B-frag layout of mfma 16x16x16 for O^T = V^T @ P^T.
// V staged via global_load_lds into subtiled [d>>4][key>>2][key&3][d&15] layout,
// PV A-frags read with ds_read_b64_tr_b16 (HW transpose). Softmax in log2 domain.

__global__ __launch_bounds__(256, 4) void attn_kernel(
    const unsigned short* __restrict__ QKV,  // [Mz][3072] bf16 (q|k|v, feature h*64+e)
    unsigned short* __restrict__ outA)       // [Mz][Dz]  bf16
{
  __shared__ unsigned short Kt[64 * 64];  // [key][d], 16B d-chunk XOR-swizzled by key&7
  __shared__ unsigned short Vs[64 * 64];  // subtiled for tr16 reads
  const int pi = blockIdx.x;
  const int hh = blockIdx.y;
  const int bb = blockIdx.z;
  const int tid = threadIdx.x;
  const int lane = tid & 63;
  const int w = tid >> 6;
  const int rsel = lane & 15;
  const int kgrp = lane >> 4;
  const int qtA = pi, qtB = 31 - pi;
  const int qgA = qtA * 64 + w * 16 + rsel;
  const int qgB = qtB * 64 + w * 16 + rsel;
  const size_t rowQA = (size_t)(bb * Sz + qgA) * 3072 + hh * 64;
  const size_t rowQB = (size_t)(bb * Sz + qgB) * 3072 + hh * 64;

  const bf16x8 qfA0 = *(const bf16x8*)&QKV[rowQA + kgrp * 8];
  const bf16x8 qfA1 = *(const bf16x8*)&QKV[rowQA + 32 + kgrp * 8];
  const bf16x8 qfB0 = *(const bf16x8*)&QKV[rowQB + kgrp * 8];
  const bf16x8 qfB1 = *(const bf16x8*)&QKV[rowQB + 32 + kgrp * 8];

  f32x4 accA[4] = {}, accB[4] = {};  // O^T: row=d=(df*16 + kgrp*4 + j), col=q=rsel
  float mA = -INFINITY, lA = 0.0f, mB = -INFINITY, lB = 0.0f;

  auto vs3 = (__attribute__((address_space(3))) unsigned short*)Vs;
  const unsigned vbase = (unsigned)(uintptr_t)vs3 + (unsigned)lane * 8u;
  constexpr float SCL = 0.18033688011112042f;  // log2(e)/sqrt(64)

  // S^T + online softmax (log2 domain) for one q-set -> P^T bf16 B-frags
  auto proc = [&](const bf16x8& qf0, const bf16x8& qf1, float& mrun, float& lrun,
                  f32x4* accO, s16x4* pb, bool edge, int qg, int kb) {
    f32x4 sc[4];
    __builtin_amdgcn_s_setprio(1);
#pragma unroll
    for (int kf = 0; kf < 4; ++kf) {
      int key = kf * 16 + rsel;
      bf16x8 k0 = *(const bf16x8*)&Kt[key * 64 + ((kgrp ^ (key & 7)) * 8)];
      bf16x8 k1 = *(const bf16x8*)&Kt[key * 64 + (((4 + kgrp) ^ (key & 7)) * 8)];
      f32x4 s = {};
      s = mfma32(k0, qf0, s);
      s = mfma32(k1, qf1, s);
      sc[kf] = s;
    }
    __builtin_amdgcn_s_setprio(0);
    float tmax = -INFINITY;
#pragma unroll
    for (int kf = 0; kf < 4; ++kf)
#pragma unroll
      for (int j = 0; j < 4; ++j) {
        float v = sc[kf][j] * SCL;
        if (edge) {
          int keyg = kb + kf * 16 + kgrp * 4 + j;
          if (keyg > qg) v = -INFINITY;
        }
        sc[kf][j] = v;
        tmax = fmaxf(tmax, v);
      }
    tmax = fmaxf(tmax, __shfl_xor(tmax, 16));
    tmax = fmaxf(tmax, __shfl_xor(tmax, 32));
    const float mnew = fmaxf(mrun, tmax);
    const float corr = exp2f(mrun - mnew);
    float psum = 0.0f;
#pragma unroll
    for (int kf = 0; kf < 4; ++kf) {
      s16x4 t;
#pragma unroll
      for (int j = 0; j < 4; ++j) {
        float e = exp2f(sc[kf][j] - mnew);
        psum += e;
        t[j] = (short)f2bu(e);
      }
      pb[kf] = t;
    }
    psum += __shfl_xor(psum, 16);
    psum += __shfl_xor(psum, 32);
    lrun = lrun * corr + psum;
    mrun = mnew;
#pragma unroll
    for (int df = 0; df < 4; ++df) accO[df] *= corr;
  };

  for (int kt = 0; kt <= qtB; ++kt) {
    const int kb = kt * 64;
    const bool doA = (kt <= qtA);
    if (kt) __syncthreads();  // prev tile's LDS reads done before overwrite
    // stage K: LDS linear, global d-chunk XOR-swizzled by key&7
#pragma unroll
    for (int r = 0; r < 2; ++r) {
      int c = r * 256 + tid;
      int key = c >> 3;
      int dcs = (c & 7) ^ (key & 7);
      GLOAD_LDS16(QKV + (size_t)(bb * Sz + kb + key) * 3072 + 1024 + hh * 64 + dcs * 8,
                  &Kt[c * 8]);
    }
    // stage V: LDS linear; source permuted so LDS holds subtiled layout
#pragma unroll
    for (int r = 0; r < 2; ++r) {
      int c = r * 256 + tid;
      int key = ((c >> 3) & 15) * 4 + ((c >> 1) & 3);
      int d = (c >> 7) * 16 + (c & 1) * 8;
      GLOAD_LDS16(QKV + (size_t)(bb * Sz + kb + key) * 3072 + 2048 + hh * 64 + d,
                  &Vs[c * 8]);
    }
    __syncthreads();

    s16x4 pbA[4], pbB[4];
    if (doA) proc(qfA0, qfA1, mA, lA, accA, pbA, kt == qtA, qgA, kb);
    proc(qfB0, qfB1, mB, lB, accB, pbB, kt == qtB, qgB, kb);

    // O^T += V^T @ P^T — V-frags shared by both q-sets
#pragma unroll
    for (int df = 0; df < 4; ++df) {
      unsigned a = vbase + df * 2048;
      s16x4 vf0 = tr16<0>(a);
      s16x4 vf1 = tr16<512>(a);
      s16x4 vf2 = tr16<1024>(a);
      s16x4 vf3 = tr16<1536>(a);
      asm volatile("s_waitcnt lgkmcnt(0)" ::: "memory");
      __builtin_amdgcn_sched_barrier(0);
      __builtin_amdgcn_s_setprio(1);
      if (doA) {
        accA[df] = mfma16(vf0, pbA[0], accA[df]);
        accA[df] = mfma16(vf1, pbA[1], accA[df]);
        accA[df] = mfma16(vf2, pbA[2], accA[df]);
        accA[df] = mfma16(vf3, pbA[3], accA[df]);
      }
      accB[df] = mfma16(vf0, pbB[0], accB[df]);
      accB[df] = mfma16(vf1, pbB[1], accB[df]);
      accB[df] = mfma16(vf2, pbB[2], accB[df]);
      accB[df] = mfma16(vf3, pbB[3], accB[df]);
      __builtin_amdgcn_s_setprio(0);
    }
  }

  auto epi = [&](const f32x4* accO, float lrun, int qg) {
    const float rl = 1.0f / lrun;
    const size_t orow = (size_t)(bb * Sz + qg) * Dz + hh * 64;
#pragma unroll
    for (int df = 0; df < 4; ++df) {
      s16x4 o;
#pragma unroll
      for (int j = 0; j < 4; ++j) o[j] = (short)f2bu(accO[df][j] * rl);
      *(s16x4*)&outA[orow + df * 16 + kgrp * 4] = o;
    }
  };
  epi(accA, lA, qgA);
  epi(accB, lB, qgB);
}

// ---------------- launch ----------------

extern "C" void kernel_launch(void* const* d_in, const int* in_sizes, int n_in,
                              void* d_out, int out_size, void* d_ws, size_t ws_size,
                              hipStream_t stream) {
  const float* x   = (const float*)d_in[0];
  // d_in[1] = mask (causal, known) — unused
  const float* wq  = (const float*)d_in[2];
  const float* wk  = (const float*)d_in[3];
  const float* wv  = (const float*)d_in[4];
  const float* wo  = (const float*)d_in[5];
  const float* w1  = (const float*)d_in[6];
  const float* b1  = (const float*)d_in[7];
  const float* w2  = (const float*)d_in[8];
  const float* b2  = (const float*)d_in[9];
  const float* g1  = (const float*)d_in[10];
  const float* be1 = (const float*)d_in[11];
  const float* g2  = (const float*)d_in[12];
  const float* be2 = (const float*)d_in[13];
  float* out = (float*)d_out;

  char* ws = (char*)d_ws;
  unsigned short* WqkvT = (unsigned short*)(ws);
  unsigned short* WoT   = (unsigned short*)(ws + 6291456);
  unsigned short* W1T   = (unsigned short*)(ws + 8388608);
  unsigned short* W2T   = (unsigned short*)(ws + 16777216);
  unsigned short* hbuf  = (unsigned short*)(ws + 25165824);
  unsigned short* big   = (unsigned short*)(ws + 41943040);  // QKV, later ff1

  dim3 tb(32, 8);
  pack_qkv<<<12288, 256, 0, stream>>>(wq, wk, wv, WqkvT);
  transpose_f32_to_bf16<<<dim3(32, 32), tb, 0, stream>>>(wo, WoT, 1024, 1024);
  transpose_f32_to_bf16<<<dim3(128, 32), tb, 0, stream>>>(w1, W1T, 1024, 4096);
  transpose_f32_to_bf16<<<dim3(32, 128), tb, 0, stream>>>(w2, W2T, 4096, 1024);

  ln_kernel<<<Mz, 256, 0, stream>>>(x, g1, be1, hbuf);
  gemm_kernel<EPI_BF16><<<dim3(24, 64), 256, 0, stream>>>(
      hbuf, WqkvT, Mz, 3072, 1024, nullptr, nullptr, big, nullptr);
  attn_kernel<<<dim3(16, 16, 4), 256, 0, stream>>>(big, hbuf);
  gemm_kernel<EPI_RES_F32><<<dim3(8, 64), 256, 0, stream>>>(
      hbuf, WoT, Mz, 1024, 1024, nullptr, x, nullptr, out);
  ln_kernel<<<Mz, 256, 0, stream>>>(out, g2, be2, hbuf);
  gemm_kernel<EPI_GELU_BF16><<<dim3(32, 64), 256, 0, stream>>>(
      hbuf, W1T, Mz, Fz, 1024, b1, nullptr, big, nullptr);
  gemm_kernel<EPI_BIAS_RES_F32><<<dim3(8, 64), 256, 0, stream>>>(
      big, W2T, Mz, 1024, Fz, b2, out, nullptr, out);
}